// Round 3
// baseline (15568.608 us; speedup 1.0000x reference)
//
#include <hip/hip_runtime.h>
#include <hip/hip_bf16.h>

// ---------------------------------------------------------------------------
// Acoustic model: embed+prenet -> bi-GRU encoder (scan over B=32, batch T=800)
// -> 2x GRU decoders (scan over T=800, batch B=32) -> linear heads.
// EXTERNAL float inputs FLOAT32; note int32 OR int64 (auto-detected).
// OUTPUT IS FLOAT32 (reference returns jnp.float32 -> harness d_out float*).
// Precision: activations fp32; MFMA bf16 hi/lo split.
// R1: both decoders in ONE dec_k launch (32 WGs) -> latency chains overlap.
// R2: fence-free handshake, relaxed agent atomics for cross-WG H.
// R3: barrier-free step loop. H carried PACKED (u32 = bf16hi<<16 | bf16lo):
//     producer does the split; consumer unpacks with v_perm straight into
//     MFMA fragments (no splitv on critical path). Per-WAVE flags (64/dec):
//     producer wave RELEASE-stores its flag (no producer barrier), consumer
//     wave polls all 64 flags with 64 lanes + __any (no consumer barrier).
//     dec_k uses no LDS so the WG barrier is gone entirely. zero_k now uses
//     agent-scope stores (kills stale-dirty-line flag clobber outliers).
// ---------------------------------------------------------------------------

typedef __bf16 bf16;
typedef bf16 bf16x8 __attribute__((ext_vector_type(8)));
typedef float f32x4 __attribute__((ext_vector_type(4)));
typedef unsigned int u32x4 __attribute__((ext_vector_type(4)));

#define BATCH 32
#define TLEN 800
#define BT (BATCH * TLEN)

__device__ __forceinline__ float bf2f(bf16 v) {
    unsigned short u = __builtin_bit_cast(unsigned short, v);
    unsigned int x = ((unsigned int)u) << 16;
    return __builtin_bit_cast(float, x);
}
__device__ __forceinline__ bf16 f2bf(float f) {
    unsigned int x = __builtin_bit_cast(unsigned int, f);
    unsigned int r = (x + 0x7FFFu + ((x >> 16) & 1u)) >> 16;
    return __builtin_bit_cast(bf16, (unsigned short)r);
}
__device__ __forceinline__ bf16x8 ld8f(const float* p) {
    f32x4 a = *(const f32x4*)p;
    f32x4 b = *(const f32x4*)(p + 4);
    bf16x8 r;
#pragma unroll
    for (int i = 0; i < 4; i++) {
        r[i] = f2bf(a[i]);
        r[i + 4] = f2bf(b[i]);
    }
    return r;
}
// split 8 floats into hi + lo bf16 (hi = rne(v), lo = rne(v - hi))
__device__ __forceinline__ void splitv(f32x4 a, f32x4 b, bf16x8& vh, bf16x8& vl) {
#pragma unroll
    for (int j = 0; j < 4; j++) {
        bf16 h0 = f2bf(a[j]);
        vh[j] = h0;
        vl[j] = f2bf(a[j] - bf2f(h0));
        bf16 h1 = f2bf(b[j]);
        vh[j + 4] = h1;
        vl[j + 4] = f2bf(b[j] - bf2f(h1));
    }
}
__device__ __forceinline__ f32x4 mfma16(bf16x8 a, bf16x8 b, f32x4 c) {
    return __builtin_amdgcn_mfma_f32_16x16x32_bf16(a, b, c, 0, 0, 0);
}
__device__ __forceinline__ float sigm(float x) { return 1.f / (1.f + __expf(-x)); }

// --- LLC-coherent (agent-scope, relaxed) helpers for cross-WG data ---------
__device__ __forceinline__ void cst_u32(unsigned int* p, unsigned int v) {
    __hip_atomic_store(p, v, __ATOMIC_RELAXED, __HIP_MEMORY_SCOPE_AGENT);
}
__device__ __forceinline__ unsigned int cld_u32(const unsigned int* p) {
    return __hip_atomic_load(p, __ATOMIC_RELAXED, __HIP_MEMORY_SCOPE_AGENT);
}
__device__ __forceinline__ unsigned long long cld_u64(const unsigned int* p) {
    return __hip_atomic_load((const unsigned long long*)p, __ATOMIC_RELAXED,
                             __HIP_MEMORY_SCOPE_AGENT);
}
// reconstruct fp32 from packed (bf16hi<<16 | bf16lo)
__device__ __forceinline__ float pk2f(unsigned int pk) {
    return bf2f(__builtin_bit_cast(bf16, (unsigned short)(pk >> 16))) +
           bf2f(__builtin_bit_cast(bf16, (unsigned short)(pk & 0xFFFFu)));
}
// unpack 4x u64 (= 8 packed u32, ascending k) into hi/lo bf16x8 fragments
__device__ __forceinline__ void unpk(const unsigned long long q[4], bf16x8& ah,
                                     bf16x8& al) {
    u32x4 hw, lw;
#pragma unroll
    for (int i = 0; i < 4; i++) {
        unsigned int x = (unsigned int)q[i];
        unsigned int y = (unsigned int)(q[i] >> 32);
        hw[i] = __builtin_amdgcn_perm(y, x, 0x07060302u);  // (y.hi<<16)|x.hi
        lw[i] = __builtin_amdgcn_perm(y, x, 0x05040100u);  // (y.lo<<16)|x.lo
    }
    ah = __builtin_bit_cast(bf16x8, hw);
    al = __builtin_bit_cast(bf16x8, lw);
}

// ---------------------------------------------------------------------------
// Prenet GEMM, 128x128 tile, K=256, split-A (fp32 src), plain-B, tanh epilogue.
// Rows b-major m = b*TC + tt.
// MODE 0: A row = note_emb[note[b*800+t0+tt]]; MODE 1: A row = asrc + m*256.
// out fp32, ldc=256.
// ---------------------------------------------------------------------------
template <int MODE>
__global__ __launch_bounds__(256) void gemm01_k(
    const int* __restrict__ note, const float* __restrict__ asrc,
    const float* __restrict__ W, const float* __restrict__ bias,
    float* __restrict__ out, int t0, int TC) {
    __shared__ bf16 Ah[128][72], Al[128][72], Bs[128][72];  // 55296 B

    const int tid = threadIdx.x;
    const int lane = tid & 63, wv = tid >> 6;
    const int wm = wv & 1, wn = wv >> 1;
    const int l15 = lane & 15, hi = lane >> 4;
    const int bm = blockIdx.x * 128, bn = blockIdx.y * 128;
    const int ch = (tid & 7) * 8, arow = tid >> 3;

    f32x4 acc[4][4] = {};
    const float* ap[4];
    if (MODE == 0) {
        int zc = 0;
        for (int i = 0; i < 64; i++) zc += (note[2 * i + 1] == 0) ? 1 : 0;
        const bool n64 = (zc >= 60);
#pragma unroll
        for (int i = 0; i < 4; i++) {
            int m = bm + arow + 32 * i;
            int b = m / TC, tt = m - b * TC;
            int idx = b * TLEN + t0 + tt;
            int id = n64 ? note[2 * idx] : note[idx];
            id = id < 0 ? 0 : (id > 127 ? 127 : id);
            ap[i] = asrc + (size_t)id * 256;
        }
    } else {
#pragma unroll
        for (int i = 0; i < 4; i++) ap[i] = asrc + (size_t)(bm + arow + 32 * i) * 256;
    }

    for (int k0 = 0; k0 < 256; k0 += 64) {
#pragma unroll
        for (int i = 0; i < 4; i++) {
            int row = arow + 32 * i;
            f32x4 va = *(const f32x4*)(ap[i] + k0 + ch);
            f32x4 vb = *(const f32x4*)(ap[i] + k0 + ch + 4);
            bf16x8 vh, vl;
            splitv(va, vb, vh, vl);
            *(bf16x8*)&Ah[row][ch] = vh;
            *(bf16x8*)&Al[row][ch] = vl;
        }
#pragma unroll
        for (int i = 0; i < 4; i++) {
            int row = arow + 32 * i;
            *(bf16x8*)&Bs[row][ch] = ld8f(W + (size_t)(bn + row) * 256 + k0 + ch);
        }
        __syncthreads();
#pragma unroll
        for (int kk = 0; kk < 64; kk += 32) {
            bf16x8 ah[4], al[4], bb[4];
#pragma unroll
            for (int mt = 0; mt < 4; mt++) {
                ah[mt] = *(const bf16x8*)&Ah[wm * 64 + mt * 16 + l15][kk + hi * 8];
                al[mt] = *(const bf16x8*)&Al[wm * 64 + mt * 16 + l15][kk + hi * 8];
            }
#pragma unroll
            for (int nt = 0; nt < 4; nt++)
                bb[nt] = *(const bf16x8*)&Bs[wn * 64 + nt * 16 + l15][kk + hi * 8];
#pragma unroll
            for (int mt = 0; mt < 4; mt++)
#pragma unroll
                for (int nt = 0; nt < 4; nt++) {
                    acc[mt][nt] = mfma16(ah[mt], bb[nt], acc[mt][nt]);
                    acc[mt][nt] = mfma16(al[mt], bb[nt], acc[mt][nt]);
                }
        }
        __syncthreads();
    }

#pragma unroll
    for (int mt = 0; mt < 4; mt++)
#pragma unroll
        for (int nt = 0; nt < 4; nt++) {
            int n = bn + wn * 64 + nt * 16 + l15;
            float bs = bias[n];
#pragma unroll
            for (int r = 0; r < 4; r++) {
                int m = bm + wm * 64 + mt * 16 + hi * 4 + r;
                out[(size_t)m * 256 + n] = tanhf(acc[mt][nt][r] + bs);
            }
        }
}

// ---------------------------------------------------------------------------
// gi GEMM: 128x64 tile, K=1088, split-A AND split-B, 3-term MFMA.
// Rows t-major m = tt*32 + b; A = [ef_c | eb_c | sig*sigW+sigB] (fp32).
// out fp32 gi, ldc=1536, bias = bih folded.
// ---------------------------------------------------------------------------
__global__ __launch_bounds__(256) void gemm2_k(
    const float* __restrict__ ef, const float* __restrict__ eb,
    const float* __restrict__ sig, const float* __restrict__ sigW,
    const float* __restrict__ sigB, const float* __restrict__ W,
    const float* __restrict__ bias, float* __restrict__ out, int t0, int TC) {
    __shared__ bf16 Ah[128][72], Al[128][72];  // 36864 B
    __shared__ bf16 Bh[64][72], Bl[64][72];    // 18432 B

    const int tid = threadIdx.x;
    const int lane = tid & 63, wv = tid >> 6;
    const int wm = wv & 1, wn = wv >> 1;
    const int l15 = lane & 15, hi = lane >> 4;
    const int bm = blockIdx.x * 128, bn = blockIdx.y * 64;
    const int ch = (tid & 7) * 8, arow = tid >> 3;

    f32x4 acc[4][2] = {};
    int rb[4];
    float sigv[4];
#pragma unroll
    for (int i = 0; i < 4; i++) {
        int m = bm + arow + 32 * i;
        int tt = m >> 5, b = m & 31;
        rb[i] = b * TC + tt;
        sigv[i] = sig[b * TLEN + t0 + tt];
    }

    for (int k0 = 0; k0 < 1088; k0 += 64) {
#pragma unroll
        for (int i = 0; i < 4; i++) {
            int row = arow + 32 * i;
            int k = k0 + ch;
            f32x4 va, vb;
            if (k < 512) {
                va = *(const f32x4*)(ef + (size_t)rb[i] * 512 + k);
                vb = *(const f32x4*)(ef + (size_t)rb[i] * 512 + k + 4);
            } else if (k < 1024) {
                va = *(const f32x4*)(eb + (size_t)rb[i] * 512 + (k - 512));
                vb = *(const f32x4*)(eb + (size_t)rb[i] * 512 + (k - 512) + 4);
            } else {
                f32x4 w0 = *(const f32x4*)(sigW + ch);
                f32x4 w1 = *(const f32x4*)(sigW + ch + 4);
                f32x4 b0 = *(const f32x4*)(sigB + ch);
                f32x4 b1 = *(const f32x4*)(sigB + ch + 4);
                float s = sigv[i];
#pragma unroll
                for (int j = 0; j < 4; j++) {
                    va[j] = s * w0[j] + b0[j];
                    vb[j] = s * w1[j] + b1[j];
                }
            }
            bf16x8 vh, vl;
            splitv(va, vb, vh, vl);
            *(bf16x8*)&Ah[row][ch] = vh;
            *(bf16x8*)&Al[row][ch] = vl;
        }
#pragma unroll
        for (int i = 0; i < 2; i++) {
            int row = arow + 32 * i;  // 0..63
            const float* src = W + (size_t)(bn + row) * 1088 + k0 + ch;
            f32x4 va = *(const f32x4*)src;
            f32x4 vb = *(const f32x4*)(src + 4);
            bf16x8 vh, vl;
            splitv(va, vb, vh, vl);
            *(bf16x8*)&Bh[row][ch] = vh;
            *(bf16x8*)&Bl[row][ch] = vl;
        }
        __syncthreads();
#pragma unroll
        for (int kk = 0; kk < 64; kk += 32) {
            bf16x8 ah[4], al[4], bh[2], bl[2];
#pragma unroll
            for (int mt = 0; mt < 4; mt++) {
                ah[mt] = *(const bf16x8*)&Ah[wm * 64 + mt * 16 + l15][kk + hi * 8];
                al[mt] = *(const bf16x8*)&Al[wm * 64 + mt * 16 + l15][kk + hi * 8];
            }
#pragma unroll
            for (int nt = 0; nt < 2; nt++) {
                bh[nt] = *(const bf16x8*)&Bh[wn * 32 + nt * 16 + l15][kk + hi * 8];
                bl[nt] = *(const bf16x8*)&Bl[wn * 32 + nt * 16 + l15][kk + hi * 8];
            }
#pragma unroll
            for (int mt = 0; mt < 4; mt++)
#pragma unroll
                for (int nt = 0; nt < 2; nt++) {
                    acc[mt][nt] = mfma16(ah[mt], bh[nt], acc[mt][nt]);
                    acc[mt][nt] = mfma16(al[mt], bh[nt], acc[mt][nt]);
                    acc[mt][nt] = mfma16(ah[mt], bl[nt], acc[mt][nt]);
                }
        }
        __syncthreads();
    }

#pragma unroll
    for (int mt = 0; mt < 4; mt++)
#pragma unroll
        for (int nt = 0; nt < 2; nt++) {
            int n = bn + wn * 32 + nt * 16 + l15;
            float bs = bias[n];
#pragma unroll
            for (int r = 0; r < 4; r++) {
                int m = bm + wm * 64 + mt * 16 + hi * 4 + r;
                out[(size_t)m * 1536 + n] = acc[mt][nt][r] + bs;
            }
        }
}

// ---------------------------------------------------------------------------
// Encoder GRU step (one scan step over B, both dirs via gridDim.z).
// hpre/ef/eb fp32, b-major chunk layouts. Split-A and split-B, 3-term.
// ---------------------------------------------------------------------------
__global__ __launch_bounds__(256) void enc_step_k(
    int step, int TC, const float* __restrict__ hpre, float* __restrict__ efb,
    float* __restrict__ ebb, const float* __restrict__ fWih,
    const float* __restrict__ fWhh, const float* __restrict__ fbih,
    const float* __restrict__ fbhh, const float* __restrict__ bWih,
    const float* __restrict__ bWhh, const float* __restrict__ bbih,
    const float* __restrict__ bbhh) {
    __shared__ bf16 As[32][72], Alo[32][72];   // 9216 B
    __shared__ bf16 Bs[96][72], Blo[96][72];   // 27648 B

    const int dir = blockIdx.z;
    const float* Wih = dir ? bWih : fWih;
    const float* Whh = dir ? bWhh : fWhh;
    const float* bih = dir ? bbih : fbih;
    const float* bhh = dir ? bbhh : fbhh;
    float* outb = dir ? ebb : efb;
    const int bsrc = dir ? (31 - step) : step;
    const int prevb = dir ? (32 - step) : (step - 1);

    const int tid = threadIdx.x;
    const int lane = tid & 63, wv = tid >> 6;
    const int mt = wv & 1, jt = wv >> 1;
    const int l15 = lane & 15, hi = lane >> 4;
    const int mtile = blockIdx.x, jtile = blockIdx.y;
    const int ch = (tid & 7) * 8, arow = tid >> 3;

    f32x4 acc_r = {}, acc_z = {}, acc_in = {}, acc_hn = {};

    const int nblocks = (step == 0) ? 4 : 12;
    for (int kb = 0; kb < nblocks; kb++) {
        int k0 = kb * 64;
        {
            int trow = mtile * 32 + arow;
            int tcl = trow < TC ? trow : TC - 1;
            const float* src = (k0 < 256)
                                   ? (hpre + ((size_t)bsrc * TC + tcl) * 256 + k0 + ch)
                                   : (outb + ((size_t)prevb * TC + tcl) * 512 + (k0 - 256) + ch);
            f32x4 va = *(const f32x4*)src;
            f32x4 vb = *(const f32x4*)(src + 4);
            bf16x8 vh, vl;
            splitv(va, vb, vh, vl);
            *(bf16x8*)&As[arow][ch] = vh;
            *(bf16x8*)&Alo[arow][ch] = vl;
        }
#pragma unroll
        for (int i = 0; i < 3; i++) {
            int row = arow + 32 * i;
            int s = row >> 5, j = row & 31;
            int wr = s * 512 + jtile * 32 + j;
            const float* src = (k0 < 256) ? (Wih + (size_t)wr * 256 + k0 + ch)
                                          : (Whh + (size_t)wr * 512 + (k0 - 256) + ch);
            f32x4 va = *(const f32x4*)src;
            f32x4 vb = *(const f32x4*)(src + 4);
            bf16x8 vh, vl;
            splitv(va, vb, vh, vl);
            *(bf16x8*)&Bs[row][ch] = vh;
            *(bf16x8*)&Blo[row][ch] = vl;
        }
        __syncthreads();
#pragma unroll
        for (int kk = 0; kk < 64; kk += 32) {
            bf16x8 a = *(const bf16x8*)&As[mt * 16 + l15][kk + hi * 8];
            bf16x8 alo = *(const bf16x8*)&Alo[mt * 16 + l15][kk + hi * 8];
            bf16x8 brh = *(const bf16x8*)&Bs[jt * 16 + l15][kk + hi * 8];
            bf16x8 brl = *(const bf16x8*)&Blo[jt * 16 + l15][kk + hi * 8];
            bf16x8 bzh = *(const bf16x8*)&Bs[32 + jt * 16 + l15][kk + hi * 8];
            bf16x8 bzl = *(const bf16x8*)&Blo[32 + jt * 16 + l15][kk + hi * 8];
            bf16x8 bnh = *(const bf16x8*)&Bs[64 + jt * 16 + l15][kk + hi * 8];
            bf16x8 bnl = *(const bf16x8*)&Blo[64 + jt * 16 + l15][kk + hi * 8];
            acc_r = mfma16(a, brh, acc_r);
            acc_r = mfma16(alo, brh, acc_r);
            acc_r = mfma16(a, brl, acc_r);
            acc_z = mfma16(a, bzh, acc_z);
            acc_z = mfma16(alo, bzh, acc_z);
            acc_z = mfma16(a, bzl, acc_z);
            if (k0 < 256) {
                acc_in = mfma16(a, bnh, acc_in);
                acc_in = mfma16(alo, bnh, acc_in);
                acc_in = mfma16(a, bnl, acc_in);
            } else {
                acc_hn = mfma16(a, bnh, acc_hn);
                acc_hn = mfma16(alo, bnh, acc_hn);
                acc_hn = mfma16(a, bnl, acc_hn);
            }
        }
        __syncthreads();
    }

    int j = jtile * 32 + jt * 16 + l15;
    float bir = bih[j] + bhh[j];
    float biz = bih[512 + j] + bhh[512 + j];
    float bin = bih[1024 + j];
    float bhn = bhh[1024 + j];
#pragma unroll
    for (int r = 0; r < 4; r++) {
        int trow = mtile * 32 + mt * 16 + hi * 4 + r;
        if (trow < TC) {
            float rr = sigm(acc_r[r] + bir);
            float zz = sigm(acc_z[r] + biz);
            float nn = tanhf(acc_in[r] + bin + rr * (acc_hn[r] + bhn));
            float hp = (step > 0) ? outb[((size_t)prevb * TC + trow) * 512 + j] : 0.f;
            outb[((size_t)bsrc * TC + trow) * 512 + j] = (1.f - zz) * nn + zz * hp;
        }
    }
}

// ---------------------------------------------------------------------------
// Persistent decoder chunk, BOTH decoders per launch (32 WGs: d=blockIdx.x>>4,
// g = blockIdx.x&15 = 32-col slice). No LDS, NO BARRIERS in the step loop.
// Whh bf16-hi fragments in registers; H carried packed u32 (bf16hi|bf16lo).
// Handshake: per-WAVE flag flg[g*4+wv] = last completed absolute step+1.
// Producer wave: 4 relaxed agent H-stores, then lane0 RELEASE agent flag
// store (release waits the wave's own vmcnt -> H visible at LLC first).
// Consumer wave: 64 lanes poll the 64 producer-wave flags, __any loop, then
// one agent ACQUIRE fence. Own H slice carried fp32 in registers (hpreg).
// Chunk boundary via Hpv (prev ring slot) + launch-order coherence.
// ---------------------------------------------------------------------------
__global__ __launch_bounds__(256, 1) void dec_k(
    const float* __restrict__ giF, const float* __restrict__ giR,
    const float* __restrict__ WhhF, const float* __restrict__ WhhR,
    const float* __restrict__ bhhF, const float* __restrict__ bhhR,
    unsigned int* __restrict__ HpkF, unsigned int* __restrict__ HpkR,
    const unsigned int* __restrict__ HpvF, const unsigned int* __restrict__ HpvR,
    int* __restrict__ flags, int t0, int TC) {
    const int d = blockIdx.x >> 4;
    const int g = blockIdx.x & 15;
    const float* gi = d ? giR : giF;
    const float* Whh = d ? WhhR : WhhF;
    const float* bhh = d ? bhhR : bhhF;
    unsigned int* Hpk = d ? HpkR : HpkF;
    const unsigned int* Hpv = d ? HpvR : HpvF;
    int* flg = flags + d * 64;

    const int tid = threadIdx.x;
    const int lane = tid & 63, wv = tid >> 6;
    const int mt = wv & 1, jt = wv >> 1;
    const int l15 = lane & 15, hi = lane >> 4;
    const int j_abs = g * 32 + jt * 16 + l15;
    const int wid = g * 4 + wv;

    bf16x8 Wf[3][16];
#pragma unroll
    for (int s = 0; s < 3; s++)
#pragma unroll
        for (int kb = 0; kb < 16; kb++)
            Wf[s][kb] = ld8f(Whh + (size_t)(s * 512 + j_abs) * 512 + kb * 32 + hi * 8);

    const float bhr = bhh[j_abs];
    const float bhz = bhh[512 + j_abs];
    const float bhn = bhh[1024 + j_abs];

    float hpreg[4] = {0.f, 0.f, 0.f, 0.f};

    for (int tt = 0; tt < TC; tt++) {
        const int t = t0 + tt;
        float gr[4], gz[4], gn[4];
#pragma unroll
        for (int r = 0; r < 4; r++) {
            int b = mt * 16 + hi * 4 + r;
            const float* gp = gi + ((size_t)tt * BATCH + b) * 1536 + j_abs;
            gr[r] = gp[0];
            gz[r] = gp[512];
            gn[r] = gp[1024];
        }

        f32x4 ar = {}, az = {}, an = {};
        float hp[4] = {0.f, 0.f, 0.f, 0.f};
        if (t > 0) {
            const unsigned int* base;
            if (tt > 0) {
                // per-wave poll: all 64 producer waves must have published t-1
                while (true) {
                    int v = __hip_atomic_load(&flg[lane], __ATOMIC_RELAXED,
                                              __HIP_MEMORY_SCOPE_AGENT);
                    if (!__any(v < t)) break;
                    __builtin_amdgcn_s_sleep(1);
                }
                __builtin_amdgcn_fence(__ATOMIC_ACQUIRE, "agent");
                base = Hpk + (size_t)(tt - 1) * BATCH * 512;
            } else {
                base = Hpv + (size_t)(TC - 1) * BATCH * 512;
            }
            const unsigned int* ap = base + (size_t)(mt * 16 + l15) * 512 + hi * 8;
#pragma unroll
            for (int half = 0; half < 2; half++) {
                unsigned long long q[8][4];
#pragma unroll
                for (int qq = 0; qq < 8; qq++) {
                    const unsigned int* pp = ap + (half * 8 + qq) * 32;
#pragma unroll
                    for (int u = 0; u < 4; u++) q[qq][u] = cld_u64(pp + 2 * u);
                }
#pragma unroll
                for (int qq = 0; qq < 8; qq++) {
                    int kb = half * 8 + qq;
                    bf16x8 ah, al;
                    unpk(q[qq], ah, al);
                    ar = mfma16(ah, Wf[0][kb], ar);
                    ar = mfma16(al, Wf[0][kb], ar);
                    az = mfma16(ah, Wf[1][kb], az);
                    az = mfma16(al, Wf[1][kb], az);
                    an = mfma16(ah, Wf[2][kb], an);
                    an = mfma16(al, Wf[2][kb], an);
                }
            }
            if (tt > 0) {
#pragma unroll
                for (int r = 0; r < 4; r++) hp[r] = hpreg[r];
            } else {
#pragma unroll
                for (int r = 0; r < 4; r++) {
                    int b = mt * 16 + hi * 4 + r;
                    hp[r] = pk2f(cld_u32(base + (size_t)b * 512 + j_abs));
                }
            }
        }
#pragma unroll
        for (int r = 0; r < 4; r++) {
            int b = mt * 16 + hi * 4 + r;
            float rr = sigm(gr[r] + ar[r] + bhr);
            float zz = sigm(gz[r] + az[r] + bhz);
            float nn = tanhf(gn[r] + rr * (an[r] + bhn));
            float hnew = (1.f - zz) * nn + zz * hp[r];
            bf16 hh = f2bf(hnew);
            bf16 hl = f2bf(hnew - bf2f(hh));
            unsigned int pk =
                ((unsigned int)__builtin_bit_cast(unsigned short, hh) << 16) |
                (unsigned int)__builtin_bit_cast(unsigned short, hl);
            cst_u32(&Hpk[((size_t)tt * BATCH + b) * 512 + j_abs], pk);
            hpreg[r] = hnew;
        }
        // per-wave release publish: waits this wave's own stores (vmcnt) only
        if (lane == 0)
            __hip_atomic_store(&flg[wid], t + 1, __ATOMIC_RELEASE,
                               __HIP_MEMORY_SCOPE_AGENT);
    }
}

// ---------------------------------------------------------------------------
// Head: out[b*800 + t0 + tt] = dot(W, H[tt*32+b][:]) + bias, H packed u32.
// ---------------------------------------------------------------------------
__global__ __launch_bounds__(256) void post_k(
    const unsigned int* __restrict__ H, const float* __restrict__ W,
    const float* __restrict__ bs, float* __restrict__ out, int t0) {
    const int wv = threadIdx.x >> 6, lane = threadIdx.x & 63;
    const int row = blockIdx.x * 4 + wv;
    const int tt = row >> 5, b = row & 31;
    const float bias = bs[0];
    const unsigned int* hp = H + (size_t)row * 512 + lane * 8;
    u32x4 p0 = *(const u32x4*)hp;
    u32x4 p1 = *(const u32x4*)(hp + 4);
    f32x4 w0 = *(const f32x4*)(W + lane * 8);
    f32x4 w1 = *(const f32x4*)(W + lane * 8 + 4);
    float s = 0.f;
#pragma unroll
    for (int i = 0; i < 4; i++) s += pk2f(p0[i]) * w0[i] + pk2f(p1[i]) * w1[i];
#pragma unroll
    for (int off = 32; off > 0; off >>= 1) s += __shfl_down(s, off);
    if (lane == 0) out[b * TLEN + t0 + tt] = s + bias;
}

__global__ void zero_k(int* __restrict__ flags) {
    int i = blockIdx.x * 256 + threadIdx.x;
    if (i < 2 * TLEN)
        __hip_atomic_store(&flags[i], 0, __ATOMIC_RELAXED,
                           __HIP_MEMORY_SCOPE_AGENT);
}

// ---------------------------------------------------------------------------
extern "C" void kernel_launch(void* const* d_in, const int* in_sizes, int n_in,
                              void* d_out, int out_size, void* d_ws, size_t ws_size,
                              hipStream_t stream) {
    const int* note = (const int*)d_in[0];
    const float* f0_prev = (const float*)d_in[1];
    const float* rmse_prev = (const float*)d_in[2];
    const float* note_emb = (const float*)d_in[3];
    const float* f0_W = (const float*)d_in[4];
    const float* f0_b = (const float*)d_in[5];
    const float* rmse_W = (const float*)d_in[6];
    const float* rmse_b = (const float*)d_in[7];
    const float* pre1_W = (const float*)d_in[8];
    const float* pre1_b = (const float*)d_in[9];
    const float* pre2_W = (const float*)d_in[10];
    const float* pre2_b = (const float*)d_in[11];
    const float* encf_Wih = (const float*)d_in[12];
    const float* encf_Whh = (const float*)d_in[13];
    const float* encf_bih = (const float*)d_in[14];
    const float* encf_bhh = (const float*)d_in[15];
    const float* encb_Wih = (const float*)d_in[16];
    const float* encb_Whh = (const float*)d_in[17];
    const float* encb_bih = (const float*)d_in[18];
    const float* encb_bhh = (const float*)d_in[19];
    const float* decf_Wih = (const float*)d_in[20];
    const float* decf_Whh = (const float*)d_in[21];
    const float* decf_bih = (const float*)d_in[22];
    const float* decf_bhh = (const float*)d_in[23];
    const float* decr_Wih = (const float*)d_in[24];
    const float* decr_Whh = (const float*)d_in[25];
    const float* decr_bih = (const float*)d_in[26];
    const float* decr_bhh = (const float*)d_in[27];
    const float* postf_W = (const float*)d_in[28];
    const float* postf_b = (const float*)d_in[29];
    const float* postr_W = (const float*)d_in[30];
    const float* postr_b = (const float*)d_in[31];
    float* out = (float*)d_out;  // reference output dtype is float32

    // --- choose chunk size TC from ws_size (multiple of 4, divides 800) ---
    // per-TC bytes: ef/eb 2*65536 + gi (BOTH decoders) 2*196608 + H rings
    // 2*slots*65536 (packed u32, same bytes as fp32)
    const int tcs[9] = {800, 400, 200, 100, 80, 40, 20, 8, 4};
    int TC = 4;
    for (int i = 0; i < 9; i++) {
        int tc = tcs[i];
        int slots = (tc == TLEN) ? 1 : 2;
        size_t need = (size_t)(2 * 65536 + 2 * 196608 + 2 * slots * 65536) * tc + 65536;
        if (ws_size >= need) { TC = tc; break; }
    }
    const int NC = TLEN / TC;
    const int slots = (NC == 1) ? 1 : 2;

    char* ws = (char*)d_ws;
    size_t off = 0;
    auto carve = [&](size_t bytes) {
        void* p = ws + off;
        off += (bytes + 255) & ~(size_t)255;
        return p;
    };
    const size_t slotB = (size_t)65536 * TC;  // TC*32*512*4 bytes
    float* ef_c = (float*)carve(slotB);
    float* eb_c = (float*)carve(slotB);
    float* giF_c = (float*)carve((size_t)196608 * TC);
    float* giR_c = (float*)carve((size_t)196608 * TC);
    unsigned int* ringF = (unsigned int*)carve(slotB * slots);
    unsigned int* ringR = (unsigned int*)carve(slotB * slots);
    int* flags = (int*)carve(2 * TLEN * 4);
    // prenet temporaries alias giF_c (dead once gi is computed): fp32
    float* t1_c = giF_c;                         // 32*TC x 256 fp32
    float* hpre_c = giF_c + (size_t)8192 * TC;   // 32*TC x 256 fp32

    zero_k<<<dim3(7), 256, 0, stream>>>(flags);

    const size_t slotE = (size_t)TC * BATCH * 512;  // elements (u32)

    for (int c = 0; c < NC; c++) {
        const int t0 = c * TC;
        const int mg = TC * 32 / 128;  // 4 | TC -> exact

        gemm01_k<0><<<dim3(mg, 2), 256, 0, stream>>>(note, note_emb, pre1_W, pre1_b,
                                                     t1_c, t0, TC);
        gemm01_k<1><<<dim3(mg, 2), 256, 0, stream>>>(nullptr, t1_c, pre2_W, pre2_b,
                                                     hpre_c, t0, TC);
        const int etiles = (TC + 31) / 32;
        for (int i = 0; i < 32; i++)
            enc_step_k<<<dim3(etiles, 16, 2), 256, 0, stream>>>(
                i, TC, hpre_c, ef_c, eb_c, encf_Wih, encf_Whh, encf_bih, encf_bhh,
                encb_Wih, encb_Whh, encb_bih, encb_bhh);

        // gi for both decoders (gemm2 writes giF after hpre/t1 are dead)
        gemm2_k<<<dim3(mg, 24), 256, 0, stream>>>(ef_c, eb_c, f0_prev, f0_W, f0_b,
                                                  decf_Wih, decf_bih, giF_c, t0, TC);
        gemm2_k<<<dim3(mg, 24), 256, 0, stream>>>(ef_c, eb_c, rmse_prev, rmse_W,
                                                  rmse_b, decr_Wih, decr_bih, giR_c,
                                                  t0, TC);

        unsigned int* HcurF = ringF + (size_t)(c & (slots - 1)) * slotE;
        const unsigned int* HprevF = ringF + (size_t)((c - 1) & (slots - 1)) * slotE;
        unsigned int* HcurR = ringR + (size_t)(c & (slots - 1)) * slotE;
        const unsigned int* HprevR = ringR + (size_t)((c - 1) & (slots - 1)) * slotE;

        // BOTH decoders in one launch: 32 WGs, d = blockIdx.x>>4
        dec_k<<<dim3(32), 256, 0, stream>>>(giF_c, giR_c, decf_Whh, decr_Whh,
                                            decf_bhh, decr_bhh, HcurF, HcurR,
                                            HprevF, HprevR, flags, t0, TC);

        post_k<<<dim3(TC * 32 / 4), 256, 0, stream>>>(HcurF, postf_W, postf_b,
                                                      out, t0);
        post_k<<<dim3(TC * 32 / 4), 256, 0, stream>>>(HcurR, postr_W, postr_b,
                                                      out + BT, t0);
    }
    (void)in_sizes; (void)n_in; (void)out_size; (void)ws_size;
}

// Round 4
// 12609.964 us; speedup vs baseline: 1.2346x; 1.2346x over previous
//
#include <hip/hip_runtime.h>
#include <hip/hip_bf16.h>

// ---------------------------------------------------------------------------
// Acoustic model: embed+prenet -> bi-GRU encoder (scan over B=32, batch T=800)
// -> 2x GRU decoders (scan over T=800, batch B=32) -> linear heads.
// EXTERNAL float inputs FLOAT32; note int32 OR int64 (auto-detected).
// OUTPUT IS FLOAT32. Precision: activations fp32; MFMA bf16 hi/lo split.
// R1: both decoders in ONE dec_k launch (32 WGs) -> latency chains overlap.
// R2: WG-level fence-free handshake (relaxed agent atomics).
// R3: packed H (u32 = bf16hi<<16|bf16lo), consumer v_perm unpack. REGRESSED
//     because per-wave RELEASE stores emitted buffer_wbl2 and consumer
//     ACQUIRE fences emitted buffer_inv -- 4x/WG/step L2 maintenance.
// R4: zero-cache-maintenance handshake. Per-wave flags (16B stride),
//     producer: explicit in-wave s_waitcnt vmcnt(0) (H sc-stores ACKed at
//     LLC) then RELAXED flag store -- no release, no wbl2. Consumer:
//     relaxed poll + compiler barrier, relaxed sc loads -- no acquire, no
//     inv. No __syncthreads in the step loop at all. Keeps packed-H path.
// ---------------------------------------------------------------------------

typedef __bf16 bf16;
typedef bf16 bf16x8 __attribute__((ext_vector_type(8)));
typedef float f32x4 __attribute__((ext_vector_type(4)));
typedef unsigned int u32x4 __attribute__((ext_vector_type(4)));

#define BATCH 32
#define TLEN 800
#define BT (BATCH * TLEN)

__device__ __forceinline__ float bf2f(bf16 v) {
    unsigned short u = __builtin_bit_cast(unsigned short, v);
    unsigned int x = ((unsigned int)u) << 16;
    return __builtin_bit_cast(float, x);
}
__device__ __forceinline__ bf16 f2bf(float f) {
    unsigned int x = __builtin_bit_cast(unsigned int, f);
    unsigned int r = (x + 0x7FFFu + ((x >> 16) & 1u)) >> 16;
    return __builtin_bit_cast(bf16, (unsigned short)r);
}
__device__ __forceinline__ bf16x8 ld8f(const float* p) {
    f32x4 a = *(const f32x4*)p;
    f32x4 b = *(const f32x4*)(p + 4);
    bf16x8 r;
#pragma unroll
    for (int i = 0; i < 4; i++) {
        r[i] = f2bf(a[i]);
        r[i + 4] = f2bf(b[i]);
    }
    return r;
}
// split 8 floats into hi + lo bf16 (hi = rne(v), lo = rne(v - hi))
__device__ __forceinline__ void splitv(f32x4 a, f32x4 b, bf16x8& vh, bf16x8& vl) {
#pragma unroll
    for (int j = 0; j < 4; j++) {
        bf16 h0 = f2bf(a[j]);
        vh[j] = h0;
        vl[j] = f2bf(a[j] - bf2f(h0));
        bf16 h1 = f2bf(b[j]);
        vh[j + 4] = h1;
        vl[j + 4] = f2bf(b[j] - bf2f(h1));
    }
}
__device__ __forceinline__ f32x4 mfma16(bf16x8 a, bf16x8 b, f32x4 c) {
    return __builtin_amdgcn_mfma_f32_16x16x32_bf16(a, b, c, 0, 0, 0);
}
__device__ __forceinline__ float sigm(float x) { return 1.f / (1.f + __expf(-x)); }

// --- LLC-coherent (agent-scope, relaxed) helpers for cross-WG data ---------
__device__ __forceinline__ void cst_u32(unsigned int* p, unsigned int v) {
    __hip_atomic_store(p, v, __ATOMIC_RELAXED, __HIP_MEMORY_SCOPE_AGENT);
}
__device__ __forceinline__ unsigned int cld_u32(const unsigned int* p) {
    return __hip_atomic_load(p, __ATOMIC_RELAXED, __HIP_MEMORY_SCOPE_AGENT);
}
__device__ __forceinline__ unsigned long long cld_u64(const unsigned int* p) {
    return __hip_atomic_load((const unsigned long long*)p, __ATOMIC_RELAXED,
                             __HIP_MEMORY_SCOPE_AGENT);
}
// reconstruct fp32 from packed (bf16hi<<16 | bf16lo)
__device__ __forceinline__ float pk2f(unsigned int pk) {
    return bf2f(__builtin_bit_cast(bf16, (unsigned short)(pk >> 16))) +
           bf2f(__builtin_bit_cast(bf16, (unsigned short)(pk & 0xFFFFu)));
}
// unpack 4x u64 (= 8 packed u32, ascending k) into hi/lo bf16x8 fragments
__device__ __forceinline__ void unpk(const unsigned long long q[4], bf16x8& ah,
                                     bf16x8& al) {
    u32x4 hw, lw;
#pragma unroll
    for (int i = 0; i < 4; i++) {
        unsigned int x = (unsigned int)q[i];
        unsigned int y = (unsigned int)(q[i] >> 32);
        hw[i] = __builtin_amdgcn_perm(y, x, 0x07060302u);  // (y.hi<<16)|x.hi
        lw[i] = __builtin_amdgcn_perm(y, x, 0x05040100u);  // (y.lo<<16)|x.lo
    }
    ah = __builtin_bit_cast(bf16x8, hw);
    al = __builtin_bit_cast(bf16x8, lw);
}

// ---------------------------------------------------------------------------
// Prenet GEMM, 128x128 tile, K=256, split-A (fp32 src), plain-B, tanh epilogue.
// Rows b-major m = b*TC + tt.
// MODE 0: A row = note_emb[note[b*800+t0+tt]]; MODE 1: A row = asrc + m*256.
// out fp32, ldc=256.
// ---------------------------------------------------------------------------
template <int MODE>
__global__ __launch_bounds__(256) void gemm01_k(
    const int* __restrict__ note, const float* __restrict__ asrc,
    const float* __restrict__ W, const float* __restrict__ bias,
    float* __restrict__ out, int t0, int TC) {
    __shared__ bf16 Ah[128][72], Al[128][72], Bs[128][72];  // 55296 B

    const int tid = threadIdx.x;
    const int lane = tid & 63, wv = tid >> 6;
    const int wm = wv & 1, wn = wv >> 1;
    const int l15 = lane & 15, hi = lane >> 4;
    const int bm = blockIdx.x * 128, bn = blockIdx.y * 128;
    const int ch = (tid & 7) * 8, arow = tid >> 3;

    f32x4 acc[4][4] = {};
    const float* ap[4];
    if (MODE == 0) {
        int zc = 0;
        for (int i = 0; i < 64; i++) zc += (note[2 * i + 1] == 0) ? 1 : 0;
        const bool n64 = (zc >= 60);
#pragma unroll
        for (int i = 0; i < 4; i++) {
            int m = bm + arow + 32 * i;
            int b = m / TC, tt = m - b * TC;
            int idx = b * TLEN + t0 + tt;
            int id = n64 ? note[2 * idx] : note[idx];
            id = id < 0 ? 0 : (id > 127 ? 127 : id);
            ap[i] = asrc + (size_t)id * 256;
        }
    } else {
#pragma unroll
        for (int i = 0; i < 4; i++) ap[i] = asrc + (size_t)(bm + arow + 32 * i) * 256;
    }

    for (int k0 = 0; k0 < 256; k0 += 64) {
#pragma unroll
        for (int i = 0; i < 4; i++) {
            int row = arow + 32 * i;
            f32x4 va = *(const f32x4*)(ap[i] + k0 + ch);
            f32x4 vb = *(const f32x4*)(ap[i] + k0 + ch + 4);
            bf16x8 vh, vl;
            splitv(va, vb, vh, vl);
            *(bf16x8*)&Ah[row][ch] = vh;
            *(bf16x8*)&Al[row][ch] = vl;
        }
#pragma unroll
        for (int i = 0; i < 4; i++) {
            int row = arow + 32 * i;
            *(bf16x8*)&Bs[row][ch] = ld8f(W + (size_t)(bn + row) * 256 + k0 + ch);
        }
        __syncthreads();
#pragma unroll
        for (int kk = 0; kk < 64; kk += 32) {
            bf16x8 ah[4], al[4], bb[4];
#pragma unroll
            for (int mt = 0; mt < 4; mt++) {
                ah[mt] = *(const bf16x8*)&Ah[wm * 64 + mt * 16 + l15][kk + hi * 8];
                al[mt] = *(const bf16x8*)&Al[wm * 64 + mt * 16 + l15][kk + hi * 8];
            }
#pragma unroll
            for (int nt = 0; nt < 4; nt++)
                bb[nt] = *(const bf16x8*)&Bs[wn * 64 + nt * 16 + l15][kk + hi * 8];
#pragma unroll
            for (int mt = 0; mt < 4; mt++)
#pragma unroll
                for (int nt = 0; nt < 4; nt++) {
                    acc[mt][nt] = mfma16(ah[mt], bb[nt], acc[mt][nt]);
                    acc[mt][nt] = mfma16(al[mt], bb[nt], acc[mt][nt]);
                }
        }
        __syncthreads();
    }

#pragma unroll
    for (int mt = 0; mt < 4; mt++)
#pragma unroll
        for (int nt = 0; nt < 4; nt++) {
            int n = bn + wn * 64 + nt * 16 + l15;
            float bs = bias[n];
#pragma unroll
            for (int r = 0; r < 4; r++) {
                int m = bm + wm * 64 + mt * 16 + hi * 4 + r;
                out[(size_t)m * 256 + n] = tanhf(acc[mt][nt][r] + bs);
            }
        }
}

// ---------------------------------------------------------------------------
// gi GEMM: 128x64 tile, K=1088, split-A AND split-B, 3-term MFMA.
// Rows t-major m = tt*32 + b; A = [ef_c | eb_c | sig*sigW+sigB] (fp32).
// out fp32 gi, ldc=1536, bias = bih folded.
// ---------------------------------------------------------------------------
__global__ __launch_bounds__(256) void gemm2_k(
    const float* __restrict__ ef, const float* __restrict__ eb,
    const float* __restrict__ sig, const float* __restrict__ sigW,
    const float* __restrict__ sigB, const float* __restrict__ W,
    const float* __restrict__ bias, float* __restrict__ out, int t0, int TC) {
    __shared__ bf16 Ah[128][72], Al[128][72];  // 36864 B
    __shared__ bf16 Bh[64][72], Bl[64][72];    // 18432 B

    const int tid = threadIdx.x;
    const int lane = tid & 63, wv = tid >> 6;
    const int wm = wv & 1, wn = wv >> 1;
    const int l15 = lane & 15, hi = lane >> 4;
    const int bm = blockIdx.x * 128, bn = blockIdx.y * 64;
    const int ch = (tid & 7) * 8, arow = tid >> 3;

    f32x4 acc[4][2] = {};
    int rb[4];
    float sigv[4];
#pragma unroll
    for (int i = 0; i < 4; i++) {
        int m = bm + arow + 32 * i;
        int tt = m >> 5, b = m & 31;
        rb[i] = b * TC + tt;
        sigv[i] = sig[b * TLEN + t0 + tt];
    }

    for (int k0 = 0; k0 < 1088; k0 += 64) {
#pragma unroll
        for (int i = 0; i < 4; i++) {
            int row = arow + 32 * i;
            int k = k0 + ch;
            f32x4 va, vb;
            if (k < 512) {
                va = *(const f32x4*)(ef + (size_t)rb[i] * 512 + k);
                vb = *(const f32x4*)(ef + (size_t)rb[i] * 512 + k + 4);
            } else if (k < 1024) {
                va = *(const f32x4*)(eb + (size_t)rb[i] * 512 + (k - 512));
                vb = *(const f32x4*)(eb + (size_t)rb[i] * 512 + (k - 512) + 4);
            } else {
                f32x4 w0 = *(const f32x4*)(sigW + ch);
                f32x4 w1 = *(const f32x4*)(sigW + ch + 4);
                f32x4 b0 = *(const f32x4*)(sigB + ch);
                f32x4 b1 = *(const f32x4*)(sigB + ch + 4);
                float s = sigv[i];
#pragma unroll
                for (int j = 0; j < 4; j++) {
                    va[j] = s * w0[j] + b0[j];
                    vb[j] = s * w1[j] + b1[j];
                }
            }
            bf16x8 vh, vl;
            splitv(va, vb, vh, vl);
            *(bf16x8*)&Ah[row][ch] = vh;
            *(bf16x8*)&Al[row][ch] = vl;
        }
#pragma unroll
        for (int i = 0; i < 2; i++) {
            int row = arow + 32 * i;  // 0..63
            const float* src = W + (size_t)(bn + row) * 1088 + k0 + ch;
            f32x4 va = *(const f32x4*)src;
            f32x4 vb = *(const f32x4*)(src + 4);
            bf16x8 vh, vl;
            splitv(va, vb, vh, vl);
            *(bf16x8*)&Bh[row][ch] = vh;
            *(bf16x8*)&Bl[row][ch] = vl;
        }
        __syncthreads();
#pragma unroll
        for (int kk = 0; kk < 64; kk += 32) {
            bf16x8 ah[4], al[4], bh[2], bl[2];
#pragma unroll
            for (int mt = 0; mt < 4; mt++) {
                ah[mt] = *(const bf16x8*)&Ah[wm * 64 + mt * 16 + l15][kk + hi * 8];
                al[mt] = *(const bf16x8*)&Al[wm * 64 + mt * 16 + l15][kk + hi * 8];
            }
#pragma unroll
            for (int nt = 0; nt < 2; nt++) {
                bh[nt] = *(const bf16x8*)&Bh[wn * 32 + nt * 16 + l15][kk + hi * 8];
                bl[nt] = *(const bf16x8*)&Bl[wn * 32 + nt * 16 + l15][kk + hi * 8];
            }
#pragma unroll
            for (int mt = 0; mt < 4; mt++)
#pragma unroll
                for (int nt = 0; nt < 2; nt++) {
                    acc[mt][nt] = mfma16(ah[mt], bh[nt], acc[mt][nt]);
                    acc[mt][nt] = mfma16(al[mt], bh[nt], acc[mt][nt]);
                    acc[mt][nt] = mfma16(ah[mt], bl[nt], acc[mt][nt]);
                }
        }
        __syncthreads();
    }

#pragma unroll
    for (int mt = 0; mt < 4; mt++)
#pragma unroll
        for (int nt = 0; nt < 2; nt++) {
            int n = bn + wn * 32 + nt * 16 + l15;
            float bs = bias[n];
#pragma unroll
            for (int r = 0; r < 4; r++) {
                int m = bm + wm * 64 + mt * 16 + hi * 4 + r;
                out[(size_t)m * 1536 + n] = acc[mt][nt][r] + bs;
            }
        }
}

// ---------------------------------------------------------------------------
// Encoder GRU step (one scan step over B, both dirs via gridDim.z).
// hpre/ef/eb fp32, b-major chunk layouts. Split-A and split-B, 3-term.
// ---------------------------------------------------------------------------
__global__ __launch_bounds__(256) void enc_step_k(
    int step, int TC, const float* __restrict__ hpre, float* __restrict__ efb,
    float* __restrict__ ebb, const float* __restrict__ fWih,
    const float* __restrict__ fWhh, const float* __restrict__ fbih,
    const float* __restrict__ fbhh, const float* __restrict__ bWih,
    const float* __restrict__ bWhh, const float* __restrict__ bbih,
    const float* __restrict__ bbhh) {
    __shared__ bf16 As[32][72], Alo[32][72];   // 9216 B
    __shared__ bf16 Bs[96][72], Blo[96][72];   // 27648 B

    const int dir = blockIdx.z;
    const float* Wih = dir ? bWih : fWih;
    const float* Whh = dir ? bWhh : fWhh;
    const float* bih = dir ? bbih : fbih;
    const float* bhh = dir ? bbhh : fbhh;
    float* outb = dir ? ebb : efb;
    const int bsrc = dir ? (31 - step) : step;
    const int prevb = dir ? (32 - step) : (step - 1);

    const int tid = threadIdx.x;
    const int lane = tid & 63, wv = tid >> 6;
    const int mt = wv & 1, jt = wv >> 1;
    const int l15 = lane & 15, hi = lane >> 4;
    const int mtile = blockIdx.x, jtile = blockIdx.y;
    const int ch = (tid & 7) * 8, arow = tid >> 3;

    f32x4 acc_r = {}, acc_z = {}, acc_in = {}, acc_hn = {};

    const int nblocks = (step == 0) ? 4 : 12;
    for (int kb = 0; kb < nblocks; kb++) {
        int k0 = kb * 64;
        {
            int trow = mtile * 32 + arow;
            int tcl = trow < TC ? trow : TC - 1;
            const float* src = (k0 < 256)
                                   ? (hpre + ((size_t)bsrc * TC + tcl) * 256 + k0 + ch)
                                   : (outb + ((size_t)prevb * TC + tcl) * 512 + (k0 - 256) + ch);
            f32x4 va = *(const f32x4*)src;
            f32x4 vb = *(const f32x4*)(src + 4);
            bf16x8 vh, vl;
            splitv(va, vb, vh, vl);
            *(bf16x8*)&As[arow][ch] = vh;
            *(bf16x8*)&Alo[arow][ch] = vl;
        }
#pragma unroll
        for (int i = 0; i < 3; i++) {
            int row = arow + 32 * i;
            int s = row >> 5, j = row & 31;
            int wr = s * 512 + jtile * 32 + j;
            const float* src = (k0 < 256) ? (Wih + (size_t)wr * 256 + k0 + ch)
                                          : (Whh + (size_t)wr * 512 + (k0 - 256) + ch);
            f32x4 va = *(const f32x4*)src;
            f32x4 vb = *(const f32x4*)(src + 4);
            bf16x8 vh, vl;
            splitv(va, vb, vh, vl);
            *(bf16x8*)&Bs[row][ch] = vh;
            *(bf16x8*)&Blo[row][ch] = vl;
        }
        __syncthreads();
#pragma unroll
        for (int kk = 0; kk < 64; kk += 32) {
            bf16x8 a = *(const bf16x8*)&As[mt * 16 + l15][kk + hi * 8];
            bf16x8 alo = *(const bf16x8*)&Alo[mt * 16 + l15][kk + hi * 8];
            bf16x8 brh = *(const bf16x8*)&Bs[jt * 16 + l15][kk + hi * 8];
            bf16x8 brl = *(const bf16x8*)&Blo[jt * 16 + l15][kk + hi * 8];
            bf16x8 bzh = *(const bf16x8*)&Bs[32 + jt * 16 + l15][kk + hi * 8];
            bf16x8 bzl = *(const bf16x8*)&Blo[32 + jt * 16 + l15][kk + hi * 8];
            bf16x8 bnh = *(const bf16x8*)&Bs[64 + jt * 16 + l15][kk + hi * 8];
            bf16x8 bnl = *(const bf16x8*)&Blo[64 + jt * 16 + l15][kk + hi * 8];
            acc_r = mfma16(a, brh, acc_r);
            acc_r = mfma16(alo, brh, acc_r);
            acc_r = mfma16(a, brl, acc_r);
            acc_z = mfma16(a, bzh, acc_z);
            acc_z = mfma16(alo, bzh, acc_z);
            acc_z = mfma16(a, bzl, acc_z);
            if (k0 < 256) {
                acc_in = mfma16(a, bnh, acc_in);
                acc_in = mfma16(alo, bnh, acc_in);
                acc_in = mfma16(a, bnl, acc_in);
            } else {
                acc_hn = mfma16(a, bnh, acc_hn);
                acc_hn = mfma16(alo, bnh, acc_hn);
                acc_hn = mfma16(a, bnl, acc_hn);
            }
        }
        __syncthreads();
    }

    int j = jtile * 32 + jt * 16 + l15;
    float bir = bih[j] + bhh[j];
    float biz = bih[512 + j] + bhh[512 + j];
    float bin = bih[1024 + j];
    float bhn = bhh[1024 + j];
#pragma unroll
    for (int r = 0; r < 4; r++) {
        int trow = mtile * 32 + mt * 16 + hi * 4 + r;
        if (trow < TC) {
            float rr = sigm(acc_r[r] + bir);
            float zz = sigm(acc_z[r] + biz);
            float nn = tanhf(acc_in[r] + bin + rr * (acc_hn[r] + bhn));
            float hp = (step > 0) ? outb[((size_t)prevb * TC + trow) * 512 + j] : 0.f;
            outb[((size_t)bsrc * TC + trow) * 512 + j] = (1.f - zz) * nn + zz * hp;
        }
    }
}

// ---------------------------------------------------------------------------
// Persistent decoder chunk, BOTH decoders per launch (32 WGs: d=blockIdx.x>>4,
// g = blockIdx.x&15 = 32-col slice). No LDS, no barriers, no cache-maintenance
// ops anywhere in the step loop. Whh bf16-hi/lo-capable fragments in regs; H
// carried packed u32 (bf16hi<<16|bf16lo), all cross-WG traffic relaxed
// agent-scope (sc-flagged, LLC-coherent).
// Handshake: per-WAVE flag slot (16 B stride to avoid line contention),
// value = last completed absolute step+1. Producer wave: sc H-stores, then
// explicit in-wave `s_waitcnt vmcnt(0)` (stores ACKed at LLC), then lane0
// RELAXED flag store -- ordering by completed-before-issue, no buffer_wbl2.
// Consumer wave: 64 lanes poll the 64 producer-wave flags (relaxed) +
// compiler reorder barrier -- no buffer_inv. Own H slice kept in registers.
// ---------------------------------------------------------------------------
__global__ __launch_bounds__(256, 1) void dec_k(
    const float* __restrict__ giF, const float* __restrict__ giR,
    const float* __restrict__ WhhF, const float* __restrict__ WhhR,
    const float* __restrict__ bhhF, const float* __restrict__ bhhR,
    unsigned int* __restrict__ HpkF, unsigned int* __restrict__ HpkR,
    const unsigned int* __restrict__ HpvF, const unsigned int* __restrict__ HpvR,
    int* __restrict__ flags, int t0, int TC) {
    const int d = blockIdx.x >> 4;
    const int g = blockIdx.x & 15;
    const float* gi = d ? giR : giF;
    const float* Whh = d ? WhhR : WhhF;
    const float* bhh = d ? bhhR : bhhF;
    unsigned int* Hpk = d ? HpkR : HpkF;
    const unsigned int* Hpv = d ? HpvR : HpvF;
    int* flg = flags + d * 256;  // 64 wave slots x 4 ints (16 B stride)

    const int tid = threadIdx.x;
    const int lane = tid & 63, wv = tid >> 6;
    const int mt = wv & 1, jt = wv >> 1;
    const int l15 = lane & 15, hi = lane >> 4;
    const int j_abs = g * 32 + jt * 16 + l15;
    const int wid = g * 4 + wv;

    bf16x8 Wf[3][16];
#pragma unroll
    for (int s = 0; s < 3; s++)
#pragma unroll
        for (int kb = 0; kb < 16; kb++)
            Wf[s][kb] = ld8f(Whh + (size_t)(s * 512 + j_abs) * 512 + kb * 32 + hi * 8);

    const float bhr = bhh[j_abs];
    const float bhz = bhh[512 + j_abs];
    const float bhn = bhh[1024 + j_abs];

    float hpreg[4] = {0.f, 0.f, 0.f, 0.f};

    for (int tt = 0; tt < TC; tt++) {
        const int t = t0 + tt;
        float gr[4], gz[4], gn[4];
#pragma unroll
        for (int r = 0; r < 4; r++) {
            int b = mt * 16 + hi * 4 + r;
            const float* gp = gi + ((size_t)tt * BATCH + b) * 1536 + j_abs;
            gr[r] = gp[0];
            gz[r] = gp[512];
            gn[r] = gp[1024];
        }

        f32x4 ar = {}, az = {}, an = {};
        float hp[4] = {0.f, 0.f, 0.f, 0.f};
        if (t > 0) {
            const unsigned int* base;
            if (tt > 0) {
                // 64 lanes poll the 64 producer-wave flags (relaxed, no fence)
                while (true) {
                    int v = __hip_atomic_load(&flg[lane * 4], __ATOMIC_RELAXED,
                                              __HIP_MEMORY_SCOPE_AGENT);
                    if (!__any(v < t)) break;
                    __builtin_amdgcn_s_sleep(1);
                }
                asm volatile("" ::: "memory");  // no H-load hoist above poll
                base = Hpk + (size_t)(tt - 1) * BATCH * 512;
            } else {
                base = Hpv + (size_t)(TC - 1) * BATCH * 512;
            }
            const unsigned int* ap = base + (size_t)(mt * 16 + l15) * 512 + hi * 8;
#pragma unroll
            for (int half = 0; half < 2; half++) {
                unsigned long long q[8][4];
#pragma unroll
                for (int qq = 0; qq < 8; qq++) {
                    const unsigned int* pp = ap + (half * 8 + qq) * 32;
#pragma unroll
                    for (int u = 0; u < 4; u++) q[qq][u] = cld_u64(pp + 2 * u);
                }
#pragma unroll
                for (int qq = 0; qq < 8; qq++) {
                    int kb = half * 8 + qq;
                    bf16x8 ah, al;
                    unpk(q[qq], ah, al);
                    ar = mfma16(ah, Wf[0][kb], ar);
                    ar = mfma16(al, Wf[0][kb], ar);
                    az = mfma16(ah, Wf[1][kb], az);
                    az = mfma16(al, Wf[1][kb], az);
                    an = mfma16(ah, Wf[2][kb], an);
                    an = mfma16(al, Wf[2][kb], an);
                }
            }
            if (tt > 0) {
#pragma unroll
                for (int r = 0; r < 4; r++) hp[r] = hpreg[r];
            } else {
#pragma unroll
                for (int r = 0; r < 4; r++) {
                    int b = mt * 16 + hi * 4 + r;
                    hp[r] = pk2f(cld_u32(base + (size_t)b * 512 + j_abs));
                }
            }
        }
#pragma unroll
        for (int r = 0; r < 4; r++) {
            int b = mt * 16 + hi * 4 + r;
            float rr = sigm(gr[r] + ar[r] + bhr);
            float zz = sigm(gz[r] + az[r] + bhz);
            float nn = tanhf(gn[r] + rr * (an[r] + bhn));
            float hnew = (1.f - zz) * nn + zz * hp[r];
            bf16 hh = f2bf(hnew);
            bf16 hl = f2bf(hnew - bf2f(hh));
            unsigned int pk =
                ((unsigned int)__builtin_bit_cast(unsigned short, hh) << 16) |
                (unsigned int)__builtin_bit_cast(unsigned short, hl);
            cst_u32(&Hpk[((size_t)tt * BATCH + b) * 512 + j_abs], pk);
            hpreg[r] = hnew;
        }
        // wave-local store drain: sc-flagged stores are ACKed at the LLC when
        // vmcnt retires. The flag store ISSUES after they COMPLETED -> no
        // release fence / buffer_wbl2 needed.
        asm volatile("s_waitcnt vmcnt(0)" ::: "memory");
        if (lane == 0)
            __hip_atomic_store(&flg[wid * 4], t + 1, __ATOMIC_RELAXED,
                               __HIP_MEMORY_SCOPE_AGENT);
    }
}

// ---------------------------------------------------------------------------
// Head: out[b*800 + t0 + tt] = dot(W, H[tt*32+b][:]) + bias, H packed u32.
// ---------------------------------------------------------------------------
__global__ __launch_bounds__(256) void post_k(
    const unsigned int* __restrict__ H, const float* __restrict__ W,
    const float* __restrict__ bs, float* __restrict__ out, int t0) {
    const int wv = threadIdx.x >> 6, lane = threadIdx.x & 63;
    const int row = blockIdx.x * 4 + wv;
    const int tt = row >> 5, b = row & 31;
    const float bias = bs[0];
    const unsigned int* hp = H + (size_t)row * 512 + lane * 8;
    u32x4 p0 = *(const u32x4*)hp;
    u32x4 p1 = *(const u32x4*)(hp + 4);
    f32x4 w0 = *(const f32x4*)(W + lane * 8);
    f32x4 w1 = *(const f32x4*)(W + lane * 8 + 4);
    float s = 0.f;
#pragma unroll
    for (int i = 0; i < 4; i++) s += pk2f(p0[i]) * w0[i] + pk2f(p1[i]) * w1[i];
#pragma unroll
    for (int off = 32; off > 0; off >>= 1) s += __shfl_down(s, off);
    if (lane == 0) out[b * TLEN + t0 + tt] = s + bias;
}

__global__ void zero_k(int* __restrict__ flags) {
    int i = blockIdx.x * 256 + threadIdx.x;
    if (i < 2 * TLEN)
        __hip_atomic_store(&flags[i], 0, __ATOMIC_RELAXED,
                           __HIP_MEMORY_SCOPE_AGENT);
}

// ---------------------------------------------------------------------------
extern "C" void kernel_launch(void* const* d_in, const int* in_sizes, int n_in,
                              void* d_out, int out_size, void* d_ws, size_t ws_size,
                              hipStream_t stream) {
    const int* note = (const int*)d_in[0];
    const float* f0_prev = (const float*)d_in[1];
    const float* rmse_prev = (const float*)d_in[2];
    const float* note_emb = (const float*)d_in[3];
    const float* f0_W = (const float*)d_in[4];
    const float* f0_b = (const float*)d_in[5];
    const float* rmse_W = (const float*)d_in[6];
    const float* rmse_b = (const float*)d_in[7];
    const float* pre1_W = (const float*)d_in[8];
    const float* pre1_b = (const float*)d_in[9];
    const float* pre2_W = (const float*)d_in[10];
    const float* pre2_b = (const float*)d_in[11];
    const float* encf_Wih = (const float*)d_in[12];
    const float* encf_Whh = (const float*)d_in[13];
    const float* encf_bih = (const float*)d_in[14];
    const float* encf_bhh = (const float*)d_in[15];
    const float* encb_Wih = (const float*)d_in[16];
    const float* encb_Whh = (const float*)d_in[17];
    const float* encb_bih = (const float*)d_in[18];
    const float* encb_bhh = (const float*)d_in[19];
    const float* decf_Wih = (const float*)d_in[20];
    const float* decf_Whh = (const float*)d_in[21];
    const float* decf_bih = (const float*)d_in[22];
    const float* decf_bhh = (const float*)d_in[23];
    const float* decr_Wih = (const float*)d_in[24];
    const float* decr_Whh = (const float*)d_in[25];
    const float* decr_bih = (const float*)d_in[26];
    const float* decr_bhh = (const float*)d_in[27];
    const float* postf_W = (const float*)d_in[28];
    const float* postf_b = (const float*)d_in[29];
    const float* postr_W = (const float*)d_in[30];
    const float* postr_b = (const float*)d_in[31];
    float* out = (float*)d_out;  // reference output dtype is float32

    // --- choose chunk size TC from ws_size (multiple of 4, divides 800) ---
    // per-TC bytes: ef/eb 2*65536 + gi (BOTH decoders) 2*196608 + H rings
    // 2*slots*65536 (packed u32, same bytes as fp32)
    const int tcs[9] = {800, 400, 200, 100, 80, 40, 20, 8, 4};
    int TC = 4;
    for (int i = 0; i < 9; i++) {
        int tc = tcs[i];
        int slots = (tc == TLEN) ? 1 : 2;
        size_t need = (size_t)(2 * 65536 + 2 * 196608 + 2 * slots * 65536) * tc + 65536;
        if (ws_size >= need) { TC = tc; break; }
    }
    const int NC = TLEN / TC;
    const int slots = (NC == 1) ? 1 : 2;

    char* ws = (char*)d_ws;
    size_t off = 0;
    auto carve = [&](size_t bytes) {
        void* p = ws + off;
        off += (bytes + 255) & ~(size_t)255;
        return p;
    };
    const size_t slotB = (size_t)65536 * TC;  // TC*32*512*4 bytes
    float* ef_c = (float*)carve(slotB);
    float* eb_c = (float*)carve(slotB);
    float* giF_c = (float*)carve((size_t)196608 * TC);
    float* giR_c = (float*)carve((size_t)196608 * TC);
    unsigned int* ringF = (unsigned int*)carve(slotB * slots);
    unsigned int* ringR = (unsigned int*)carve(slotB * slots);
    int* flags = (int*)carve(2 * TLEN * 4);
    // prenet temporaries alias giF_c (dead once gi is computed): fp32
    float* t1_c = giF_c;                         // 32*TC x 256 fp32
    float* hpre_c = giF_c + (size_t)8192 * TC;   // 32*TC x 256 fp32

    zero_k<<<dim3(7), 256, 0, stream>>>(flags);

    const size_t slotE = (size_t)TC * BATCH * 512;  // elements (u32)

    for (int c = 0; c < NC; c++) {
        const int t0 = c * TC;
        const int mg = TC * 32 / 128;  // 4 | TC -> exact

        gemm01_k<0><<<dim3(mg, 2), 256, 0, stream>>>(note, note_emb, pre1_W, pre1_b,
                                                     t1_c, t0, TC);
        gemm01_k<1><<<dim3(mg, 2), 256, 0, stream>>>(nullptr, t1_c, pre2_W, pre2_b,
                                                     hpre_c, t0, TC);
        const int etiles = (TC + 31) / 32;
        for (int i = 0; i < 32; i++)
            enc_step_k<<<dim3(etiles, 16, 2), 256, 0, stream>>>(
                i, TC, hpre_c, ef_c, eb_c, encf_Wih, encf_Whh, encf_bih, encf_bhh,
                encb_Wih, encb_Whh, encb_bih, encb_bhh);

        // gi for both decoders (gemm2 writes giF after hpre/t1 are dead)
        gemm2_k<<<dim3(mg, 24), 256, 0, stream>>>(ef_c, eb_c, f0_prev, f0_W, f0_b,
                                                  decf_Wih, decf_bih, giF_c, t0, TC);
        gemm2_k<<<dim3(mg, 24), 256, 0, stream>>>(ef_c, eb_c, rmse_prev, rmse_W,
                                                  rmse_b, decr_Wih, decr_bih, giR_c,
                                                  t0, TC);

        unsigned int* HcurF = ringF + (size_t)(c & (slots - 1)) * slotE;
        const unsigned int* HprevF = ringF + (size_t)((c - 1) & (slots - 1)) * slotE;
        unsigned int* HcurR = ringR + (size_t)(c & (slots - 1)) * slotE;
        const unsigned int* HprevR = ringR + (size_t)((c - 1) & (slots - 1)) * slotE;

        // BOTH decoders in one launch: 32 WGs, d = blockIdx.x>>4
        dec_k<<<dim3(32), 256, 0, stream>>>(giF_c, giR_c, decf_Whh, decr_Whh,
                                            decf_bhh, decr_bhh, HcurF, HcurR,
                                            HprevF, HprevR, flags, t0, TC);

        post_k<<<dim3(TC * 32 / 4), 256, 0, stream>>>(HcurF, postf_W, postf_b,
                                                      out, t0);
        post_k<<<dim3(TC * 32 / 4), 256, 0, stream>>>(HcurR, postr_W, postr_b,
                                                      out + BT, t0);
    }
    (void)in_sizes; (void)n_in; (void)out_size; (void)ws_size;
}